// Round 1
// baseline (125.628 us; speedup 1.0000x reference)
//
#include <hip/hip_runtime.h>

#define B 8
#define N 2048
#define KF 256
#define DF 64
#define LOG2E 1.44269504088896340736f
#define NR 2049   // prefix-table rows per batch (row 2048 = total/zero row)

typedef __attribute__((ext_vector_type(8))) short short8;   // 8 bf16 (4 VGPRs)
typedef __attribute__((ext_vector_type(4))) float float4v;  // MFMA C/D frag

__device__ __forceinline__ float fexp2(float x) {
#if __has_builtin(__builtin_amdgcn_exp2f)
    return __builtin_amdgcn_exp2f(x);
#else
    return exp2f(x);
#endif
}
__device__ __forceinline__ float eluf(float x) {
    return x > 0.f ? x : fexp2(x * LOG2E) - 1.0f;
}
// float -> bf16 bits, round-half-up
__device__ __forceinline__ short bf16r(float x) {
    unsigned u = __float_as_uint(x);
    return (short)((u + 0x8000u) >> 16);
}
#define DOT4(c, u, p) \
    p = fmaf(c.x, u.x, fmaf(c.y, u.y, fmaf(c.z, u.z, fmaf(c.w, u.w, p))));

// ---- A: Wh = h@W via MFMA + fused f1/f2 + fused W-prep (R11 structure).
// Output change vs baseline: plain f32 Wh[b][i][64], coalesced 256-B row
// stores (the scattered bf16 chunk layout is no longer needed — the N^2
// consumer is gone). ----
__global__ __launch_bounds__(256) void k_wh(const float* __restrict__ h,
                                            const float* __restrict__ W,
                                            const float* __restrict__ a,
                                            float* __restrict__ Wh,
                                            float* __restrict__ f1,
                                            float* __restrict__ f2) {
    __shared__ __align__(16) unsigned char smem[34816];  // phase union
    short* lwt  = (short*)smem;               // A: [64 n][256 k] bf16 W^T (32 KB)
    float* lv   = (float*)(smem + 32768);     // A: [2][256] v1,v2 (2 KB)
    float* lred = (float*)smem;               // B: [4 wv][16*66] (16.9 KB)
    float* lp   = (float*)(smem + 16896);     // B: [2][4][16]

    int t = threadIdx.x;
    int wv = t >> 6, lane = t & 63;
    int n15 = lane & 15, q = lane >> 4;
    int bx = blockIdx.x;

    // issue tile-0 h loads early (independent of W staging)
    const float* hr = h + ((long)bx * 32 + n15) * KF + wv * 64 + q * 8;
    float4 c0 = *(const float4*)(hr);
    float4 c1 = *(const float4*)(hr + 4);
    float4 c2 = *(const float4*)(hr + 32);
    float4 c3 = *(const float4*)(hr + 36);

    // ---- in-block W prep: thread t owns W row k=t ----
    {
        const float4* wr4 = (const float4*)(W + t * DF);
        float s1 = 0.f, s2 = 0.f;
        #pragma unroll
        for (int c = 0; c < 16; c++) {
            float4 w4 = wr4[c];
            float4 a1v = *(const float4*)(a + 4 * c);        // uniform -> s_load
            float4 a2v = *(const float4*)(a + DF + 4 * c);
            lwt[(4 * c + 0) * 256 + t] = bf16r(w4.x);        // 2-way write: free
            lwt[(4 * c + 1) * 256 + t] = bf16r(w4.y);
            lwt[(4 * c + 2) * 256 + t] = bf16r(w4.z);
            lwt[(4 * c + 3) * 256 + t] = bf16r(w4.w);
            s1 = fmaf(w4.x, a1v.x, fmaf(w4.y, a1v.y, fmaf(w4.z, a1v.z, fmaf(w4.w, a1v.w, s1))));
            s2 = fmaf(w4.x, a2v.x, fmaf(w4.y, a2v.y, fmaf(w4.z, a2v.z, fmaf(w4.w, a2v.w, s2))));
        }
        lv[t] = s1;
        lv[256 + t] = s2;
    }
    __syncthreads();

    // hoist loop-invariant B-frags + v12 (one-time LDS reads)
    const short* bq = lwt + n15 * 256 + wv * 64 + q * 8;
    short8 s0b0 = *(const short8*)(bq);
    short8 s0b1 = *(const short8*)(bq + 16 * 256);
    short8 s0b2 = *(const short8*)(bq + 32 * 256);
    short8 s0b3 = *(const short8*)(bq + 48 * 256);
    short8 s1b0 = *(const short8*)(bq + 32);
    short8 s1b1 = *(const short8*)(bq + 16 * 256 + 32);
    short8 s1b2 = *(const short8*)(bq + 32 * 256 + 32);
    short8 s1b3 = *(const short8*)(bq + 48 * 256 + 32);
    const float* vv = lv + wv * 64 + q * 8;
    float4 u00 = *(const float4*)(vv);
    float4 u01 = *(const float4*)(vv + 4);
    float4 u10 = *(const float4*)(vv + 32);
    float4 u11 = *(const float4*)(vv + 36);
    float4 x00 = *(const float4*)(vv + 256);
    float4 x01 = *(const float4*)(vv + 256 + 4);
    float4 x10 = *(const float4*)(vv + 256 + 32);
    float4 x11 = *(const float4*)(vv + 256 + 36);
    __syncthreads();   // lwt/lv dead; lred region reusable

    #pragma unroll
    for (int rt = 0; rt < 2; rt++) {
        float4 m0, m1, m2, m3;
        if (rt < 1) {                         // prefetch next 16-row tile
            const float* hn = hr + 16 * KF;
            m0 = *(const float4*)(hn);
            m1 = *(const float4*)(hn + 4);
            m2 = *(const float4*)(hn + 32);
            m3 = *(const float4*)(hn + 36);
        }
        float p1 = 0.f, p2 = 0.f;
        DOT4(c0, u00, p1) DOT4(c1, u01, p1) DOT4(c2, u10, p1) DOT4(c3, u11, p1)
        DOT4(c0, x00, p2) DOT4(c1, x01, p2) DOT4(c2, x10, p2) DOT4(c3, x11, p2)

        short8 af0 = { bf16r(c0.x), bf16r(c0.y), bf16r(c0.z), bf16r(c0.w),
                       bf16r(c1.x), bf16r(c1.y), bf16r(c1.z), bf16r(c1.w) };
        short8 af1 = { bf16r(c2.x), bf16r(c2.y), bf16r(c2.z), bf16r(c2.w),
                       bf16r(c3.x), bf16r(c3.y), bf16r(c3.z), bf16r(c3.w) };
        float4v acc0 = {0.f, 0.f, 0.f, 0.f}, acc1 = acc0, acc2 = acc0, acc3 = acc0;
        acc0 = __builtin_amdgcn_mfma_f32_16x16x32_bf16(af0, s0b0, acc0, 0, 0, 0);
        acc0 = __builtin_amdgcn_mfma_f32_16x16x32_bf16(af1, s1b0, acc0, 0, 0, 0);
        acc1 = __builtin_amdgcn_mfma_f32_16x16x32_bf16(af0, s0b1, acc1, 0, 0, 0);
        acc1 = __builtin_amdgcn_mfma_f32_16x16x32_bf16(af1, s1b1, acc1, 0, 0, 0);
        acc2 = __builtin_amdgcn_mfma_f32_16x16x32_bf16(af0, s0b2, acc2, 0, 0, 0);
        acc2 = __builtin_amdgcn_mfma_f32_16x16x32_bf16(af1, s1b2, acc2, 0, 0, 0);
        acc3 = __builtin_amdgcn_mfma_f32_16x16x32_bf16(af0, s0b3, acc3, 0, 0, 0);
        acc3 = __builtin_amdgcn_mfma_f32_16x16x32_bf16(af1, s1b3, acc3, 0, 0, 0);

        #define STASH(nb, A)                                                  \
            {                                                                 \
                _Pragma("unroll")                                             \
                for (int r = 0; r < 4; r++)                                   \
                    lred[wv * 1056 + (q * 4 + r) * 66 + nb * 16 + n15] = A[r]; \
            }
        STASH(0, acc0) STASH(1, acc1) STASH(2, acc2) STASH(3, acc3)
        #undef STASH
        p1 += __shfl_xor(p1, 16, 64); p1 += __shfl_xor(p1, 32, 64);
        p2 += __shfl_xor(p2, 16, 64); p2 += __shfl_xor(p2, 32, 64);
        if (q == 0) { lp[wv * 16 + n15] = p1; lp[64 + wv * 16 + n15] = p2; }
        __syncthreads();

        long i0 = (long)bx * 32 + rt * 16;
        int d = t & 63, ig = t >> 6;
        int bb = (int)(i0 >> 11);
        int il = (int)(i0 & (N - 1));
        float s0 = 0.f, s1 = 0.f, s2 = 0.f, s3 = 0.f;
        #pragma unroll
        for (int w = 0; w < 4; w++) {
            const float* lr = lred + w * 1056 + (ig * 4) * 66 + d;
            s0 += lr[0]; s1 += lr[66]; s2 += lr[132]; s3 += lr[198];
        }
        float* wp = Wh + ((long)bb * N + il + ig * 4) * DF + d;
        wp[0]      = s0;
        wp[DF]     = s1;
        wp[2 * DF] = s2;
        wp[3 * DF] = s3;

        if (t < 16) {
            f1[i0 + t] = lp[t] + lp[16 + t] + lp[32 + t] + lp[48 + t];
        } else if (t < 32) {
            int tt = t + 48;   // 64 + (t-16)
            f2[i0 + t - 16] = lp[tt] + lp[16 + tt] + lp[32 + tt] + lp[48 + tt];
        }
        __syncthreads();
        c0 = m0; c1 = m1; c2 = m2; c3 = m3;
    }
}

// ---- B: sort + prefix tables. e[i,j] = f1_i + f2_j is rank-1 before the
// LeakyReLU; the branch is decided by sign(f1_i + f2_j). Sorting j by f2
// turns each row's branch set into a prefix/suffix split, so the whole
// attention contraction reduces to two weighted prefix scans of Wh plus a
// per-row threshold lookup. One block per (d-slice, batch); the sort/den
// phases are redundantly replicated across the 4 d-slices (cheap).
// Outputs: tIdx[b][i] (threshold), SSg[b][t][d] (suffix of g*Wh),
// PSgs[b][t][d] (exclusive prefix of gs*Wh), rows t in [0,2048]. ----
__global__ __launch_bounds__(1024) void k_prep(const float* __restrict__ Wh,
                                               const float* __restrict__ f1,
                                               const float* __restrict__ f2,
                                               int* __restrict__ tIdx,
                                               float* __restrict__ SSg,
                                               float* __restrict__ PSgs) {
    __shared__ float sv[2048];                 // sorted f2 values
    __shared__ int   si[2048];                 // original j for sorted pos
    __shared__ float gA[2048];                 // g  (also temp seg sums)
    __shared__ float gsA[2048];                // gs (also temp seg sums)
    __shared__ __align__(16) unsigned char un[25088];
    float* f1s  = (float*)un;                  // [2048] sorted f1
    float* ps1  = (float*)(un + 8192);         // [2049] excl prefix of E1
    float* ps1s = (float*)(un + 16640);        // [2049] excl prefix of E1s
    float* sG   = (float*)un;                  // [64][16] scan seg sums (f1s dead)
    float* sGs  = (float*)(un + 4096);

    int t = threadIdx.x;
    int dsl = blockIdx.x, b = blockIdx.y;
    const float* f1g = f1 + b * N;
    const float* f2g = f2 + b * N;

    sv[t] = f2g[t];  sv[t + 1024] = f2g[t + 1024];
    si[t] = t;       si[t + 1024] = t + 1024;
    f1s[t] = f1g[t]; f1s[t + 1024] = f1g[t + 1024];
    __syncthreads();

    // bitonic sort ascending: (sv,si) pairs and f1s values, same network
    for (int k = 2; k <= 2048; k <<= 1) {
        for (int j = k >> 1; j > 0; j >>= 1) {
            int i1 = ((t & ~(j - 1)) << 1) | (t & (j - 1));
            int i2 = i1 | j;
            bool up = (i1 & k) == 0;
            float a  = sv[i1],  c  = sv[i2];
            int   ia = si[i1],  ic = si[i2];
            if ((a > c) == up) { sv[i1] = c; sv[i2] = a; si[i1] = ic; si[i2] = ia; }
            float fa = f1s[i1], fc = f1s[i2];
            if ((fa > fc) == up) { f1s[i1] = fc; f1s[i2] = fa; }
            __syncthreads();
        }
    }

    // scalar exclusive prefix sums of E1 = exp(f1s), E1s = exp(0.2 f1s)
    if (t < 64) {
        float a1 = 0.f, a2 = 0.f;
        #pragma unroll 4
        for (int x = 0; x < 32; x++) {
            float v = f1s[t * 32 + x];
            a1 += fexp2(v * LOG2E);
            a2 += fexp2(v * 0.2f * LOG2E);
        }
        gA[t] = a1; gsA[t] = a2;               // temp segment sums
    }
    __syncthreads();
    if (t < 64) {
        float o1 = 0.f, o2 = 0.f;
        for (int s = 0; s < t; s++) { o1 += gA[s]; o2 += gsA[s]; }
        for (int x = 0; x < 32; x++) {
            int p = t * 32 + x;
            ps1[p] = o1; ps1s[p] = o2;
            float v = f1s[p];
            o1 += fexp2(v * LOG2E);
            o2 += fexp2(v * 0.2f * LOG2E);
        }
        if (t == 63) { ps1[2048] = o1; ps1s[2048] = o2; }
    }
    __syncthreads();

    // per sorted-f2 position: den via threshold on sorted f1 -> g, gs
    float tot1 = ps1[2048], tot1s = ps1s[2048];
    for (int p = t; p < 2048; p += 1024) {
        float v   = sv[p];
        float E2  = fexp2(v * LOG2E);
        float E2s = fexp2(v * 0.2f * LOG2E);
        float key = -v;
        int lo = 0, hi = 2048;
        while (lo < hi) { int mid = (lo + hi) >> 1; if (f1s[mid] < key) lo = mid + 1; else hi = mid; }
        float den = E2 * (tot1 - ps1[lo]) + E2s * ps1s[lo];
        float rr = 1.0f / den;
        gA[p] = E2 * rr; gsA[p] = E2s * rr;
    }
    // per original row i: threshold t_i = #{j : f2_j < -f1_i} (dsl 0 only)
    if (dsl == 0) {
        for (int i = t; i < 2048; i += 1024) {
            float key = -f1g[i];
            int lo = 0, hi = 2048;
            while (lo < hi) { int mid = (lo + hi) >> 1; if (sv[mid] < key) lo = mid + 1; else hi = mid; }
            tIdx[b * N + i] = lo;
        }
    }
    __syncthreads();   // gA/gsA ready; f1s/ps1 dead -> sG/sGs region live

    // weighted scans of Wh rows in sorted order, this block's 16-d slice.
    // thread = (seg in [0,64), dl in [0,16)); 32 rows per segment.
    int seg = t >> 4, dl = t & 15;
    int d = dsl * 16 + dl;
    const float* whb = Wh + (((long)b) << 11) * DF;
    float w[32];
    float ag = 0.f, ags = 0.f;
    #pragma unroll
    for (int x = 0; x < 32; x++) {
        int p = seg * 32 + x;
        float wv = whb[si[p] * DF + d];
        w[x] = wv;
        ag  += gA[p] * wv;
        ags += gsA[p] * wv;
    }
    sG[seg * 16 + dl] = ag; sGs[seg * 16 + dl] = ags;
    __syncthreads();
    float og = 0.f, ogs = 0.f, tot = 0.f, tots = 0.f;
    for (int s = 0; s < 64; s++) {
        float vg = sG[s * 16 + dl], vgs = sGs[s * 16 + dl];
        if (s < seg) { og += vg; ogs += vgs; }
        tot += vg; tots += vgs;
    }
    (void)tots;
    float* pg  = SSg  + ((long)b * NR) * DF + d;
    float* pgs = PSgs + ((long)b * NR) * DF + d;
    #pragma unroll
    for (int x = 0; x < 32; x++) {
        int p = seg * 32 + x;
        pg [(long)p * DF] = tot - og;          // suffix  sum_{p'>=p} g*Wh
        pgs[(long)p * DF] = ogs;               // excl prefix_{p'<p} gs*Wh
        og  += gA[p]  * w[x];
        ogs += gsA[p] * w[x];
    }
    if (seg == 63) { pg[2048L * DF] = tot - og; pgs[2048L * DF] = ogs; }
}

// ---- C: output. O[i,:] = elu( E1_i * SSg[t_i,:] + E1s_i * PSgs[t_i,:] ).
// 64 rows/block; per row: 2 gathered 256-B table rows + 2 FMA + elu. ----
__global__ __launch_bounds__(256) void k_out(const float* __restrict__ f1,
                                             const int* __restrict__ tIdx,
                                             const float* __restrict__ SSg,
                                             const float* __restrict__ PSgs,
                                             float* __restrict__ out) {
    int t = threadIdx.x;
    int b = blockIdx.y;
    int i0 = blockIdx.x * 64;
    int rr = t >> 6, d = t & 63;
    const float* sgB = SSg  + ((long)b * NR) * DF + d;
    const float* pgB = PSgs + ((long)b * NR) * DF + d;
    float* ob = out + ((long)b * N + i0) * DF + d;
    #pragma unroll
    for (int kk = 0; kk < 16; kk++) {
        int r = rr + kk * 4;
        int ti = tIdx[b * N + i0 + r];                 // wave-uniform
        float v = f1[b * N + i0 + r];
        float e1  = fexp2(v * LOG2E);
        float e1s = fexp2(v * 0.2f * LOG2E);
        float x = e1 * sgB[(long)ti * DF] + e1s * pgB[(long)ti * DF];
        ob[(long)r * DF] = eluf(x);
    }
}

extern "C" void kernel_launch(void* const* d_in, const int* in_sizes, int n_in,
                              void* d_out, int out_size, void* d_ws, size_t ws_size,
                              hipStream_t stream) {
    const float* h = (const float*)d_in[0];
    const float* W = (const float*)d_in[1];
    const float* a = (const float*)d_in[2];
    float* out = (float*)d_out;

    char* ws = (char*)d_ws;
    const size_t NB = (size_t)B * N;          // 16384 rows
    size_t off = 0;
    float* Wh   = (float*)(ws + off); off += NB * DF * sizeof(float);          // 4 MB
    float* f1   = (float*)(ws + off); off += NB * sizeof(float);
    float* f2   = (float*)(ws + off); off += NB * sizeof(float);
    int*   tIdx = (int*)  (ws + off); off += NB * sizeof(int);
    float* SSg  = (float*)(ws + off); off += (size_t)B * NR * DF * sizeof(float); // 4.2 MB
    float* PSgs = (float*)(ws + off); off += (size_t)B * NR * DF * sizeof(float); // 4.2 MB
    (void)off; (void)ws_size;

    k_wh<<<NB / 32, 256, 0, stream>>>(h, W, a, Wh, f1, f2);
    k_prep<<<dim3(4, B), 1024, 0, stream>>>(Wh, f1, f2, tIdx, SSg, PSgs);
    k_out<<<dim3(N / 64, B), 256, 0, stream>>>(f1, tIdx, SSg, PSgs, out);
}

// Round 2
// 101.555 us; speedup vs baseline: 1.2370x; 1.2370x over previous
//
#include <hip/hip_runtime.h>

#define B 8
#define N 2048
#define KF 256
#define DF 64
#define LOG2E 1.44269504088896340736f
#define NR 2049   // prefix-table rows per batch (row 2048 = total/zero row)

typedef __attribute__((ext_vector_type(8))) short short8;   // 8 bf16 (4 VGPRs)
typedef __attribute__((ext_vector_type(4))) float float4v;  // MFMA C/D frag

__device__ __forceinline__ float fexp2(float x) {
#if __has_builtin(__builtin_amdgcn_exp2f)
    return __builtin_amdgcn_exp2f(x);
#else
    return exp2f(x);
#endif
}
__device__ __forceinline__ float eluf(float x) {
    return x > 0.f ? x : fexp2(x * LOG2E) - 1.0f;
}
// float -> bf16 bits, round-half-up
__device__ __forceinline__ short bf16r(float x) {
    unsigned u = __float_as_uint(x);
    return (short)((u + 0x8000u) >> 16);
}
#define DOT4(c, u, p) \
    p = fmaf(c.x, u.x, fmaf(c.y, u.y, fmaf(c.z, u.z, fmaf(c.w, u.w, p))));

// ---- A: Wh = h@W via MFMA + fused f1/f2 + fused W-prep (R11 structure).
// Plain f32 Wh[b][i][64], coalesced 256-B row stores. ----
__global__ __launch_bounds__(256) void k_wh(const float* __restrict__ h,
                                            const float* __restrict__ W,
                                            const float* __restrict__ a,
                                            float* __restrict__ Wh,
                                            float* __restrict__ f1,
                                            float* __restrict__ f2) {
    __shared__ __align__(16) unsigned char smem[34816];  // phase union
    short* lwt  = (short*)smem;               // A: [64 n][256 k] bf16 W^T (32 KB)
    float* lv   = (float*)(smem + 32768);     // A: [2][256] v1,v2 (2 KB)
    float* lred = (float*)smem;               // B: [4 wv][16*66] (16.9 KB)
    float* lp   = (float*)(smem + 16896);     // B: [2][4][16]

    int t = threadIdx.x;
    int wv = t >> 6, lane = t & 63;
    int n15 = lane & 15, q = lane >> 4;
    int bx = blockIdx.x;

    // issue tile-0 h loads early (independent of W staging)
    const float* hr = h + ((long)bx * 32 + n15) * KF + wv * 64 + q * 8;
    float4 c0 = *(const float4*)(hr);
    float4 c1 = *(const float4*)(hr + 4);
    float4 c2 = *(const float4*)(hr + 32);
    float4 c3 = *(const float4*)(hr + 36);

    // ---- in-block W prep: thread t owns W row k=t ----
    {
        const float4* wr4 = (const float4*)(W + t * DF);
        float s1 = 0.f, s2 = 0.f;
        #pragma unroll
        for (int c = 0; c < 16; c++) {
            float4 w4 = wr4[c];
            float4 a1v = *(const float4*)(a + 4 * c);        // uniform -> s_load
            float4 a2v = *(const float4*)(a + DF + 4 * c);
            lwt[(4 * c + 0) * 256 + t] = bf16r(w4.x);        // 2-way write: free
            lwt[(4 * c + 1) * 256 + t] = bf16r(w4.y);
            lwt[(4 * c + 2) * 256 + t] = bf16r(w4.z);
            lwt[(4 * c + 3) * 256 + t] = bf16r(w4.w);
            s1 = fmaf(w4.x, a1v.x, fmaf(w4.y, a1v.y, fmaf(w4.z, a1v.z, fmaf(w4.w, a1v.w, s1))));
            s2 = fmaf(w4.x, a2v.x, fmaf(w4.y, a2v.y, fmaf(w4.z, a2v.z, fmaf(w4.w, a2v.w, s2))));
        }
        lv[t] = s1;
        lv[256 + t] = s2;
    }
    __syncthreads();

    // hoist loop-invariant B-frags + v12 (one-time LDS reads)
    const short* bq = lwt + n15 * 256 + wv * 64 + q * 8;
    short8 s0b0 = *(const short8*)(bq);
    short8 s0b1 = *(const short8*)(bq + 16 * 256);
    short8 s0b2 = *(const short8*)(bq + 32 * 256);
    short8 s0b3 = *(const short8*)(bq + 48 * 256);
    short8 s1b0 = *(const short8*)(bq + 32);
    short8 s1b1 = *(const short8*)(bq + 16 * 256 + 32);
    short8 s1b2 = *(const short8*)(bq + 32 * 256 + 32);
    short8 s1b3 = *(const short8*)(bq + 48 * 256 + 32);
    const float* vv = lv + wv * 64 + q * 8;
    float4 u00 = *(const float4*)(vv);
    float4 u01 = *(const float4*)(vv + 4);
    float4 u10 = *(const float4*)(vv + 32);
    float4 u11 = *(const float4*)(vv + 36);
    float4 x00 = *(const float4*)(vv + 256);
    float4 x01 = *(const float4*)(vv + 256 + 4);
    float4 x10 = *(const float4*)(vv + 256 + 32);
    float4 x11 = *(const float4*)(vv + 256 + 36);
    __syncthreads();   // lwt/lv dead; lred region reusable

    #pragma unroll
    for (int rt = 0; rt < 2; rt++) {
        float4 m0, m1, m2, m3;
        if (rt < 1) {                         // prefetch next 16-row tile
            const float* hn = hr + 16 * KF;
            m0 = *(const float4*)(hn);
            m1 = *(const float4*)(hn + 4);
            m2 = *(const float4*)(hn + 32);
            m3 = *(const float4*)(hn + 36);
        }
        float p1 = 0.f, p2 = 0.f;
        DOT4(c0, u00, p1) DOT4(c1, u01, p1) DOT4(c2, u10, p1) DOT4(c3, u11, p1)
        DOT4(c0, x00, p2) DOT4(c1, x01, p2) DOT4(c2, x10, p2) DOT4(c3, x11, p2)

        short8 af0 = { bf16r(c0.x), bf16r(c0.y), bf16r(c0.z), bf16r(c0.w),
                       bf16r(c1.x), bf16r(c1.y), bf16r(c1.z), bf16r(c1.w) };
        short8 af1 = { bf16r(c2.x), bf16r(c2.y), bf16r(c2.z), bf16r(c2.w),
                       bf16r(c3.x), bf16r(c3.y), bf16r(c3.z), bf16r(c3.w) };
        float4v acc0 = {0.f, 0.f, 0.f, 0.f}, acc1 = acc0, acc2 = acc0, acc3 = acc0;
        acc0 = __builtin_amdgcn_mfma_f32_16x16x32_bf16(af0, s0b0, acc0, 0, 0, 0);
        acc0 = __builtin_amdgcn_mfma_f32_16x16x32_bf16(af1, s1b0, acc0, 0, 0, 0);
        acc1 = __builtin_amdgcn_mfma_f32_16x16x32_bf16(af0, s0b1, acc1, 0, 0, 0);
        acc1 = __builtin_amdgcn_mfma_f32_16x16x32_bf16(af1, s1b1, acc1, 0, 0, 0);
        acc2 = __builtin_amdgcn_mfma_f32_16x16x32_bf16(af0, s0b2, acc2, 0, 0, 0);
        acc2 = __builtin_amdgcn_mfma_f32_16x16x32_bf16(af1, s1b2, acc2, 0, 0, 0);
        acc3 = __builtin_amdgcn_mfma_f32_16x16x32_bf16(af0, s0b3, acc3, 0, 0, 0);
        acc3 = __builtin_amdgcn_mfma_f32_16x16x32_bf16(af1, s1b3, acc3, 0, 0, 0);

        #define STASH(nb, A)                                                  \
            {                                                                 \
                _Pragma("unroll")                                             \
                for (int r = 0; r < 4; r++)                                   \
                    lred[wv * 1056 + (q * 4 + r) * 66 + nb * 16 + n15] = A[r]; \
            }
        STASH(0, acc0) STASH(1, acc1) STASH(2, acc2) STASH(3, acc3)
        #undef STASH
        p1 += __shfl_xor(p1, 16, 64); p1 += __shfl_xor(p1, 32, 64);
        p2 += __shfl_xor(p2, 16, 64); p2 += __shfl_xor(p2, 32, 64);
        if (q == 0) { lp[wv * 16 + n15] = p1; lp[64 + wv * 16 + n15] = p2; }
        __syncthreads();

        long i0 = (long)bx * 32 + rt * 16;
        int d = t & 63, ig = t >> 6;
        int bb = (int)(i0 >> 11);
        int il = (int)(i0 & (N - 1));
        float s0 = 0.f, s1 = 0.f, s2 = 0.f, s3 = 0.f;
        #pragma unroll
        for (int w = 0; w < 4; w++) {
            const float* lr = lred + w * 1056 + (ig * 4) * 66 + d;
            s0 += lr[0]; s1 += lr[66]; s2 += lr[132]; s3 += lr[198];
        }
        float* wp = Wh + ((long)bb * N + il + ig * 4) * DF + d;
        wp[0]      = s0;
        wp[DF]     = s1;
        wp[2 * DF] = s2;
        wp[3 * DF] = s3;

        if (t < 16) {
            f1[i0 + t] = lp[t] + lp[16 + t] + lp[32 + t] + lp[48 + t];
        } else if (t < 32) {
            int tt = t + 48;   // 64 + (t-16)
            f2[i0 + t - 16] = lp[tt] + lp[16 + tt] + lp[32 + tt] + lp[48 + tt];
        }
        __syncthreads();
        c0 = m0; c1 = m1; c2 = m2; c3 = m3;
    }
}

// ---- B: brute-force ranks + direct denominators (NO SORT). For each row
// index within a batch: rank of f2_j (tie-break by index -> exact
// permutation), den_j via masked sums of E1/E1s, tIdx_i = #{j: f2_j < -f1_i}.
// All inner reads are wave-broadcast LDS (conflict-free). Scatter writes
// materialize the sorted order: si[rank]=j, gA[rank]=E2/den, gsA[rank]=E2s/den.
// Grid (32, B) x 512 thr: block owns 64 rows, 8 quarter-waves split the
// 2048-long count loop. ----
__global__ __launch_bounds__(512) void k_rank(const float* __restrict__ f1,
                                              const float* __restrict__ f2,
                                              int* __restrict__ tIdx,
                                              int* __restrict__ si,
                                              float* __restrict__ gA,
                                              float* __restrict__ gsA) {
    __shared__ __align__(16) float4 qv[2048];   // {f1, E1, E1s, f2}
    __shared__ unsigned u2[2048];               // sortable bits of f2
    __shared__ float rS1[8][64], rS1s[8][64];
    __shared__ int   rC2[8][64], rC3[8][64];

    int t = threadIdx.x;
    int b = blockIdx.y;
    int base = blockIdx.x * 64;
    const float* f1g = f1 + b * N;
    const float* f2g = f2 + b * N;

    #pragma unroll
    for (int r = 0; r < 4; r++) {
        int idx = t + r * 512;
        float v1 = f1g[idx], v2 = f2g[idx];
        qv[idx] = make_float4(v1, fexp2(v1 * LOG2E), fexp2(v1 * 0.2f * LOG2E), v2);
        unsigned ub = __float_as_uint(v2);
        u2[idx] = ub ^ (((unsigned)((int)ub >> 31)) | 0x80000000u);
    }
    __syncthreads();

    int jl = t & 63, qt = t >> 6;       // qt wave-uniform
    int j = base + jl;
    float4 qj = qv[j];
    unsigned uj = u2[j];
    float negf2 = -qj.w, negf1 = -qj.x;
    int c2 = 0, c3 = 0;
    float S1 = 0.f, S1s = 0.f;
    int p0 = qt * 256;
    #pragma unroll 4
    for (int p = p0; p < p0 + 256; p++) {
        float4 qa = qv[p];              // broadcast b128
        unsigned up = u2[p];            // broadcast b32
        c2 += (up < uj || (up == uj && p < j)) ? 1 : 0;
        bool c = qa.x < negf2;          // f1_p < -f2_j
        S1  += c ? 0.f : qa.y;
        S1s += c ? qa.z : 0.f;
        c3 += (qa.w < negf1) ? 1 : 0;
    }
    rC2[qt][jl] = c2; rC3[qt][jl] = c3;
    rS1[qt][jl] = S1; rS1s[qt][jl] = S1s;
    __syncthreads();

    if (t < 64) {
        int j2 = base + t;
        float4 qj2 = qv[j2];
        int rank = 0, ti = 0;
        float s1 = 0.f, s1s = 0.f;
        #pragma unroll
        for (int k = 0; k < 8; k++) {
            rank += rC2[k][t]; ti += rC3[k][t];
            s1 += rS1[k][t];   s1s += rS1s[k][t];
        }
        float E2  = fexp2(qj2.w * LOG2E);
        float E2s = fexp2(qj2.w * 0.2f * LOG2E);
        float rr = 1.0f / (E2 * s1 + E2s * s1s);
        tIdx[b * N + j2] = ti;
        si [b * N + rank] = j2;          // scatter: sorted order
        gA [b * N + rank] = E2 * rr;
        gsA[b * N + rank] = E2s * rr;
    }
}

// ---- C: segment sums of the weighted rows in sorted order. seg = 32
// positions; segG[b][seg][d] = sum g_p * Wh[si[p]][d] (and gs variant).
// Grid (16, B) x 256 thr: 4 waves/block, wave = one segment, lane = d.
// Row loads are 256-B coalesced; si/g/gs are broadcast loads. ----
__global__ __launch_bounds__(256) void k_seg(const float* __restrict__ Wh,
                                             const int* __restrict__ si,
                                             const float* __restrict__ gA,
                                             const float* __restrict__ gsA,
                                             float* __restrict__ segG,
                                             float* __restrict__ segGs) {
    int t = threadIdx.x;
    int d = t & 63, sq = t >> 6;
    int seg = blockIdx.x * 4 + sq, b = blockIdx.y;
    const int*   sib = si  + b * N;
    const float* ga  = gA  + b * N;
    const float* gsa = gsA + b * N;
    const float* whb = Wh + (((long)b) << 11) * DF;
    float sg = 0.f, sgs = 0.f;
    #pragma unroll 8
    for (int x = 0; x < 32; x++) {
        int p = seg * 32 + x;
        int r = sib[p];
        float wv = whb[r * DF + d];
        sg  = fmaf(ga[p],  wv, sg);
        sgs = fmaf(gsa[p], wv, sgs);
    }
    segG [(b * 64 + seg) * DF + d] = sg;
    segGs[(b * 64 + seg) * DF + d] = sgs;
}

// ---- D: table emission. Per (b,seg) block: seg-level prefix/total from
// segG/segGs, then within-seg serial walk writing SSg (suffix of g*Wh)
// and PSgs (exclusive prefix of gs*Wh) rows, 256-B coalesced stores.
// 256 thr = 64 d x 4 subs of 8 positions. ----
__global__ __launch_bounds__(256) void k_tab(const float* __restrict__ Wh,
                                             const int* __restrict__ si,
                                             const float* __restrict__ gA,
                                             const float* __restrict__ gsA,
                                             const float* __restrict__ segG,
                                             const float* __restrict__ segGs,
                                             float* __restrict__ SSg,
                                             float* __restrict__ PSgs) {
    __shared__ float lPG[4][64], lPGs[4][64];   // sub-partial seg prefixes
    __shared__ float lTG[4][64], lTGs[4][64];   // sub-partial seg totals
    __shared__ float wG[4][64],  wGs[4][64];    // within-seg sub sums
    int t = threadIdx.x;
    int d = t & 63, sub = t >> 6;
    int seg = blockIdx.x, b = blockIdx.y;

    const float* sgb  = segG  + (b * 64) * DF + d;
    const float* sgsb = segGs + (b * 64) * DF + d;
    float pg = 0.f, pgs = 0.f, tg = 0.f, tgs = 0.f;
    #pragma unroll
    for (int k = 0; k < 16; k++) {
        int s = sub * 16 + k;
        float vg = sgb[s * DF], vgs = sgsb[s * DF];
        tg += vg; tgs += vgs;
        if (s < seg) { pg += vg; pgs += vgs; }
    }
    lPG[sub][d] = pg; lPGs[sub][d] = pgs;
    lTG[sub][d] = tg; lTGs[sub][d] = tgs;

    int p0 = seg * 32 + sub * 8;
    const int*   sib = si  + b * N;
    const float* ga  = gA  + b * N;
    const float* gsa = gsA + b * N;
    const float* whb = Wh + (((long)b) << 11) * DF;
    float rows[8], gv[8], gsv[8];
    float sg = 0.f, sgs = 0.f;
    #pragma unroll
    for (int x = 0; x < 8; x++) {
        int p = p0 + x;
        int r = sib[p];
        float wv = whb[r * DF + d];
        rows[x] = wv; gv[x] = ga[p]; gsv[x] = gsa[p];
        sg  = fmaf(gv[x],  wv, sg);
        sgs = fmaf(gsv[x], wv, sgs);
    }
    wG[sub][d] = sg; wGs[sub][d] = sgs;
    __syncthreads();

    float totG  = lTG[0][d] + lTG[1][d] + lTG[2][d] + lTG[3][d];
    float totGs = lTGs[0][d] + lTGs[1][d] + lTGs[2][d] + lTGs[3][d];
    float baseG  = lPG[0][d] + lPG[1][d] + lPG[2][d] + lPG[3][d];
    float baseGs = lPGs[0][d] + lPGs[1][d] + lPGs[2][d] + lPGs[3][d];
    #pragma unroll
    for (int k = 0; k < 3; k++) {
        if (k < sub) { baseG += wG[k][d]; baseGs += wGs[k][d]; }
    }

    float* ssb = SSg  + ((long)b * NR) * DF + d;
    float* psb = PSgs + ((long)b * NR) * DF + d;
    float rg = baseG, rgs = baseGs;
    #pragma unroll
    for (int x = 0; x < 8; x++) {
        long p = p0 + x;
        ssb[p * DF] = totG - rg;
        psb[p * DF] = rgs;
        rg  = fmaf(gv[x],  rows[x], rg);
        rgs = fmaf(gsv[x], rows[x], rgs);
    }
    if (seg == 63 && sub == 3) {
        ssb[2048L * DF] = 0.f;          // exact zero suffix
        psb[2048L * DF] = rgs;          // full prefix total
    }
}

// ---- E: output. O[i,:] = elu( E1_i * SSg[t_i,:] + E1s_i * PSgs[t_i,:] ). ----
__global__ __launch_bounds__(256) void k_out(const float* __restrict__ f1,
                                             const int* __restrict__ tIdx,
                                             const float* __restrict__ SSg,
                                             const float* __restrict__ PSgs,
                                             float* __restrict__ out) {
    int t = threadIdx.x;
    int b = blockIdx.y;
    int i0 = blockIdx.x * 64;
    int rr = t >> 6, d = t & 63;
    const float* sgB = SSg  + ((long)b * NR) * DF + d;
    const float* pgB = PSgs + ((long)b * NR) * DF + d;
    float* ob = out + ((long)b * N + i0) * DF + d;
    #pragma unroll
    for (int kk = 0; kk < 16; kk++) {
        int r = rr + kk * 4;
        int ti = tIdx[b * N + i0 + r];                 // wave-uniform
        float v = f1[b * N + i0 + r];
        float e1  = fexp2(v * LOG2E);
        float e1s = fexp2(v * 0.2f * LOG2E);
        float x = e1 * sgB[(long)ti * DF] + e1s * pgB[(long)ti * DF];
        ob[(long)r * DF] = eluf(x);
    }
}

extern "C" void kernel_launch(void* const* d_in, const int* in_sizes, int n_in,
                              void* d_out, int out_size, void* d_ws, size_t ws_size,
                              hipStream_t stream) {
    const float* h = (const float*)d_in[0];
    const float* W = (const float*)d_in[1];
    const float* a = (const float*)d_in[2];
    float* out = (float*)d_out;

    char* ws = (char*)d_ws;
    const size_t NB = (size_t)B * N;          // 16384 rows
    size_t off = 0;
    float* Wh    = (float*)(ws + off); off += NB * DF * sizeof(float);         // 4 MB
    float* f1    = (float*)(ws + off); off += NB * sizeof(float);
    float* f2    = (float*)(ws + off); off += NB * sizeof(float);
    int*   tIdx  = (int*)  (ws + off); off += NB * sizeof(int);
    int*   si    = (int*)  (ws + off); off += NB * sizeof(int);
    float* gA    = (float*)(ws + off); off += NB * sizeof(float);
    float* gsA   = (float*)(ws + off); off += NB * sizeof(float);
    float* segG  = (float*)(ws + off); off += (size_t)B * 64 * DF * sizeof(float); // 128 KB
    float* segGs = (float*)(ws + off); off += (size_t)B * 64 * DF * sizeof(float);
    float* SSg   = (float*)(ws + off); off += (size_t)B * NR * DF * sizeof(float); // 4.2 MB
    float* PSgs  = (float*)(ws + off); off += (size_t)B * NR * DF * sizeof(float); // 4.2 MB
    (void)off; (void)ws_size;

    k_wh  <<<NB / 32, 256, 0, stream>>>(h, W, a, Wh, f1, f2);
    k_rank<<<dim3(N / 64, B), 512, 0, stream>>>(f1, f2, tIdx, si, gA, gsA);
    k_seg <<<dim3(16, B), 256, 0, stream>>>(Wh, si, gA, gsA, segG, segGs);
    k_tab <<<dim3(64, B), 256, 0, stream>>>(Wh, si, gA, gsA, segG, segGs, SSg, PSgs);
    k_out <<<dim3(N / 64, B), 256, 0, stream>>>(f1, tIdx, SSg, PSgs, out);
}